// Round 3
// baseline (414.563 us; speedup 1.0000x reference)
//
#include <hip/hip_runtime.h>
#include <cstdint>

// Problem constants
#define LSEQ 1024
#define BATCH 16
#define NIN 1024
#define NOUT 512
#define KGATE 5
#define NCOL (NOUT * KGATE)           // 2560
#define MTOT (LSEQ * BATCH)           // 16384
#define CHAINS (BATCH * NOUT)         // 8192
#define OUT_GCS (LSEQ * BATCH * NOUT) // 8388608
#define SEG 32                        // segments
#define SLEN 32                       // steps per segment
#define PLANE ((size_t)MTOT * NOUT)   // elements per gate plane (8M)
#define SMP ((size_t)SEG * CHAINS)    // elements per segmap plane (256K)

// GEMM geometry: m97-family TLP structure, 1-ahead staged dbuf
#define BM 256
#define BN 128
#define BK 32
#define NT (NIN / BK)                 // 32 K-tiles

typedef _Float16 f16x8 __attribute__((ext_vector_type(8)));
typedef _Float16 f16x4 __attribute__((ext_vector_type(4)));
typedef _Float16 f16x2 __attribute__((ext_vector_type(2)));
typedef float f32x4 __attribute__((ext_vector_type(4)));

__device__ __forceinline__ void async16(const void* g, void* l) {
    __builtin_amdgcn_global_load_lds(
        (const __attribute__((address_space(1))) void*)(uintptr_t)g,
        (__attribute__((address_space(3))) void*)(uintptr_t)l,
        16, 0, 0);
}

__device__ __forceinline__ float fsigmoid(float x) {
    return 1.0f / (1.0f + __expf(-x));
}

// ---------------- Kernel 1: convert x fp32 -> f16 (8 elems/thread) ----------------
__global__ void convert_x_k(const float* __restrict__ x, _Float16* __restrict__ xb, int n8) {
    int i = blockIdx.x * blockDim.x + threadIdx.x;
    if (i < n8) {
        float4 a = ((const float4*)x)[2 * i];
        float4 b = ((const float4*)x)[2 * i + 1];
        f16x8 h;
        h[0] = (_Float16)a.x; h[1] = (_Float16)a.y; h[2] = (_Float16)a.z; h[3] = (_Float16)a.w;
        h[4] = (_Float16)b.x; h[5] = (_Float16)b.y; h[6] = (_Float16)b.z; h[7] = (_Float16)b.w;
        ((f16x8*)xb)[i] = h;
    }
}

// ---------------- Kernel 2: transpose+convert+PERMUTE weight ----------------
// w [1024][2560] f32 -> wT [2560][1024] f16; orig col c=n*5+g -> row' = g*512+n
__global__ __launch_bounds__(256) void transpose_w_k(const float* __restrict__ w, _Float16* __restrict__ wT) {
    __shared__ float lds[32][33];
    int t = threadIdx.x;
    int col = t & 31;
    int rowg = t >> 5;
    int n0 = blockIdx.x * 32;
    int k0 = blockIdx.y * 32;
#pragma unroll
    for (int i = 0; i < 4; i++) {
        int r = rowg + i * 8;
        lds[r][col] = w[(size_t)(k0 + r) * NCOL + n0 + col];
    }
    __syncthreads();
#pragma unroll
    for (int i = 0; i < 4; i++) {
        int r = rowg + i * 8;
        int c = n0 + r;
        int row = (c % 5) * NOUT + (c / 5);
        wT[(size_t)row * NIN + k0 + col] = (_Float16)lds[col][r];
    }
}

// ---------------- Kernel 3: MFMA GEMM 256x128, BK=32, 1-ahead dbuf, 3 blocks/CU ----------------
// A: xb [16384][1024] f16; BT: wT [2560][1024] f16 (gate-plane-permuted cols)
// Per tile: stage(t+1 -> other slot) issued FIRST (max latency distance), then
// ds_read 12 b128 (XOR-swizzled) + 32 MFMA, then ONE __syncthreads
// (vmcnt+lgkm drain + barrier = slot handoff). Staging latency is covered by
// current tile's compute + 3-block/CU TLP (m114 overlap).
// LDS swizzle: 16B-chunk k' = k ^ ((row>>1)&3). Combined with the row-parity
// bank bit, 16 consecutive rows hit bank-quad 4*(row&1) + (k^((row>>1)&3)):
// all 8 quads, 2 lanes each -> conflict-free b128 (2-way is free, m136).
// MFMA operands SWAPPED (bf, af) -> acc holds C^T fragments: each lane owns 4
// consecutive n at fixed m -> f16x4 stores (4x fewer insts, 32B segments).
__global__ __launch_bounds__(256, 3) void gemm_gates_k(const _Float16* __restrict__ A,
                                                       const _Float16* __restrict__ BT,
                                                       const float* __restrict__ bias,
                                                       _Float16* __restrict__ planes) {
    // 48 KiB: A slots [2][8192] f16 at byte 0; B slots [2][4096] f16 at byte 32768
    __shared__ _Float16 lds[24576];
    const int t = threadIdx.x;
    const int w = t >> 6, lane = t & 63;
    const int q = lane >> 4, r16 = lane & 15;
    const int wm = (w >> 1) * 128, wn = (w & 1) * 64;
    const int m0 = blockIdx.x * BM, n0 = blockIdx.y * BN;

    // Loop-invariant per-lane LDS read byte bases (row*64B + swizzled 16B chunk).
    // Read rows differ from r16 by multiples of 16 -> (row>>1)&3 == (r16>>1)&3.
    const int swz = (q ^ ((r16 >> 1) & 3)) << 4;
    const int aBase = (wm + r16) * 64 + swz;            // + i*1024 + cur*16384
    const int bBase = 32768 + (wn + r16) * 64 + swz;    // + j*1024 + cur*8192

    // Staging: A 1024 chunks (4/thread), B 512 chunks (2/thread); chunk c = t + L*256,
    // r = c>>2 = rS + L*64, kc = c&3 = t&3; source chunk pre-swizzled kc^((r>>1)&3)
    // (lane-constant across L since L*64 is a multiple of 8 rows).
    const int rS = t >> 2;
    const int skS = (t & 3) ^ ((rS >> 1) & 3);
    const _Float16* aS = A + (size_t)(m0 + rS) * NIN + skS * 8;
    const _Float16* bS = BT + (size_t)(n0 + rS) * NIN + skS * 8;
    char* const ldsb = (char*)lds;
    const int aDst = t * 16;             // + L*4096 + nxt*16384
    const int bDst = 32768 + t * 16;     // + L*4096 + nxt*8192

    auto stage = [&](int tile, int nxt) {
        const _Float16* ap = aS + (size_t)tile * BK;
        const _Float16* bp = bS + (size_t)tile * BK;
#pragma unroll
        for (int L = 0; L < 4; L++)
            async16(ap + (size_t)L * 64 * NIN, ldsb + nxt * 16384 + aDst + L * 4096);
#pragma unroll
        for (int L = 0; L < 2; L++)
            async16(bp + (size_t)L * 64 * NIN, ldsb + nxt * 8192 + bDst + L * 4096);
    };

    f32x4 acc[8][4] = {};

    // Prologue: stage tile 0 -> slot 0
    stage(0, 0);
    __syncthreads();

#pragma unroll 2
    for (int tt = 0; tt < NT; tt++) {
        const int cur = tt & 1;
        // stage next tile into the other slot FIRST (max issue->wait distance)
        if (tt + 1 < NT) stage(tt + 1, cur ^ 1);

        f16x8 af[8], bf[4];
        const char* ab = ldsb + cur * 16384 + aBase;
        const char* bb = ldsb + cur * 8192 + bBase;
#pragma unroll
        for (int i = 0; i < 8; i++) af[i] = *(const f16x8*)(ab + i * 1024);
#pragma unroll
        for (int j = 0; j < 4; j++) bf[j] = *(const f16x8*)(bb + j * 1024);

        __builtin_amdgcn_s_setprio(1);
#pragma unroll
        for (int i = 0; i < 8; i++)
#pragma unroll
            for (int j = 0; j < 4; j++)
                acc[i][j] = __builtin_amdgcn_mfma_f32_16x16x32_f16(bf[j], af[i], acc[i][j], 0, 0, 0);
        __builtin_amdgcn_s_setprio(0);

        // one barrier per tile: drains vmcnt (next tile staged) + slot handoff
        __syncthreads();
    }

    // Epilogue: acc[i][j] = C^T frag: m = wm + i*16 + r16, n = wn + j*16 + q*4 + reg
    const int g = n0 >> 9;            // block spans 128 cols within one 512-gate
    const int nb = n0 & (NOUT - 1);
    _Float16* plane = planes + (size_t)g * PLANE;
#pragma unroll
    for (int i = 0; i < 8; i++) {
        int m = m0 + wm + i * 16 + r16;
        _Float16* prow = plane + (size_t)m * NOUT + nb;
#pragma unroll
        for (int j = 0; j < 4; j++) {
            int nn = wn + j * 16 + q * 4;
            float4 bv = *(const float4*)(bias + n0 + nn);
            f16x4 hv;
#pragma unroll
            for (int reg = 0; reg < 4; reg++) {
                float v = acc[i][j][reg];
                float b = (reg == 0) ? bv.x : (reg == 1) ? bv.y : (reg == 2) ? bv.z : bv.w;
                if (g >= 2) v = fsigmoid(v + b);
                hv[reg] = (_Float16)v;
            }
            *(f16x4*)(prow + nn) = hv;
        }
    }
}

// ---------------- Kernel 4a: compose per-segment affine maps ----------------
// 2 chains/thread (8 waves/CU) + 1-deep register prefetch of next step's vectors.
// map: c' = A c + b, A=[[f1,0],[u2,f2]], b=[u1, eps*u2]
// SM planes: 0:a11 1:a21 2:a22 3:b1 4:b2, each [SEG][CHAINS] f32
__global__ __launch_bounds__(256) void compose_k(const _Float16* __restrict__ planes,
                                                 const float* __restrict__ beps,
                                                 float* __restrict__ SM) {
    int u = blockIdx.x * 256 + threadIdx.x;       // 0 .. SEG*CHAINS/2 - 1
    int t2 = u & (CHAINS / 2 - 1);
    int s = u >> 12;
    int tch = t2 << 1;
    int n = tch & (NOUT - 1);
    float eps[2] = { fsigmoid(beps[n]), fsigmoid(beps[n + 1]) };
    float a11[2] = {1.0f, 1.0f}, a21[2] = {}, a22[2] = {1.0f, 1.0f}, b1[2] = {}, b2[2] = {};
    const f16x2* p2 = (const f16x2*)planes;
    const size_t P2E = PLANE >> 1;
    const size_t estep = CHAINS >> 1;
    size_t e = ((size_t)(s * SLEN) * CHAINS + tch) >> 1;
    f16x2 u1n = p2[e], u2n = p2[P2E + e], f1n = p2[2 * P2E + e], f2n = p2[3 * P2E + e];
#pragma unroll 4
    for (int j = 0; j < SLEN; j++) {
        f16x2 u1c = u1n, u2c = u2n, f1c = f1n, f2c = f2n;
        if (j + 1 < SLEN) {
            e += estep;
            u1n = p2[e]; u2n = p2[P2E + e]; f1n = p2[2 * P2E + e]; f2n = p2[3 * P2E + e];
        }
#pragma unroll
        for (int c = 0; c < 2; c++) {
            float u1 = (float)u1c[c], u2 = (float)u2c[c];
            float f1 = (float)f1c[c], f2 = (float)f2c[c];
            float na11 = f1 * a11[c];
            float na21 = fmaf(u2, a11[c], f2 * a21[c]);
            float na22 = f2 * a22[c];
            float nb1  = fmaf(f1, b1[c], u1);
            float nb2  = fmaf(u2, b1[c], fmaf(f2, b2[c], eps[c] * u2));
            a11[c] = na11; a21[c] = na21; a22[c] = na22; b1[c] = nb1; b2[c] = nb2;
        }
    }
    size_t idx = (size_t)s * CHAINS + tch;
    *(float2*)(SM + idx)           = make_float2(a11[0], a11[1]);
    *(float2*)(SM + SMP + idx)     = make_float2(a21[0], a21[1]);
    *(float2*)(SM + 2 * SMP + idx) = make_float2(a22[0], a22[1]);
    *(float2*)(SM + 3 * SMP + idx) = make_float2(b1[0], b1[1]);
    *(float2*)(SM + 4 * SMP + idx) = make_float2(b2[0], b2[1]);
}

// ---------------- Kernel 4b: sequential scan over segment maps (prefetched) ----------------
__global__ __launch_bounds__(256) void segscan_k(const float* __restrict__ SM,
                                                 float* __restrict__ segc,
                                                 float* __restrict__ out) {
    int t = blockIdx.x * 256 + threadIdx.x;  // 0..8191
    float c1 = 0.0f, c2 = 0.0f;
    float a11n = SM[t], a21n = SM[SMP + t], a22n = SM[2 * SMP + t];
    float b1n = SM[3 * SMP + t], b2n = SM[4 * SMP + t];
#pragma unroll
    for (int s = 0; s < SEG; s++) {
        float a11 = a11n, a21 = a21n, a22 = a22n, b1 = b1n, b2 = b2n;
        if (s + 1 < SEG) {
            size_t nx = (size_t)(s + 1) * CHAINS + t;
            a11n = SM[nx]; a21n = SM[SMP + nx]; a22n = SM[2 * SMP + nx];
            b1n = SM[3 * SMP + nx]; b2n = SM[4 * SMP + nx];
        }
        size_t idx = (size_t)s * CHAINS + t;
        segc[idx] = c1;
        segc[SMP + idx] = c2;
        float c1n = fmaf(a11, c1, b1);
        float c2n = fmaf(a21, c1, fmaf(a22, c2, b2));
        c1 = c1n; c2 = c2n;
    }
    out[OUT_GCS + t] = c1;
    out[OUT_GCS + CHAINS + t] = c2;
}

// ---------------- Kernel 4c: apply within segments + fused output ----------------
// 2 chains/thread + 1-deep register prefetch.
__global__ __launch_bounds__(256) void apply_k(const _Float16* __restrict__ planes,
                                               const float* __restrict__ segc,
                                               const float* __restrict__ beps,
                                               const float* __restrict__ bfin,
                                               float* __restrict__ out) {
    int u = blockIdx.x * 256 + threadIdx.x;
    int t2 = u & (CHAINS / 2 - 1);
    int s = u >> 12;
    int tch = t2 << 1;
    int n = tch & (NOUT - 1);
    float eps[2], rho0[2], rho1[2], c1[2], c2[2];
#pragma unroll
    for (int c = 0; c < 2; c++) {
        eps[c]  = fsigmoid(beps[n + c]);
        rho0[c] = 2.0f * fsigmoid(bfin[2 * (n + c)]);
        rho1[c] = 2.0f * fsigmoid(bfin[2 * (n + c) + 1]);
    }
    size_t idx = (size_t)s * CHAINS + tch;
    float2 c1v = *(const float2*)(segc + idx);
    float2 c2v = *(const float2*)(segc + SMP + idx);
    c1[0] = c1v.x; c1[1] = c1v.y; c2[0] = c2v.x; c2[1] = c2v.y;
    const f16x2* p2 = (const f16x2*)planes;
    const size_t P2E = PLANE >> 1;
    const size_t estep = CHAINS >> 1;
    size_t e2 = ((size_t)(s * SLEN) * CHAINS + tch) >> 1;
    size_t eo = (size_t)(s * SLEN) * CHAINS + tch;
    f16x2 u1n = p2[e2], u2n = p2[P2E + e2], f1n = p2[2 * P2E + e2],
          f2n = p2[3 * P2E + e2], on = p2[4 * P2E + e2];
#pragma unroll 4
    for (int j = 0; j < SLEN; j++) {
        f16x2 u1c = u1n, u2c = u2n, f1c = f1n, f2c = f2n, oc = on;
        if (j + 1 < SLEN) {
            e2 += estep;
            u1n = p2[e2]; u2n = p2[P2E + e2]; f1n = p2[2 * P2E + e2];
            f2n = p2[3 * P2E + e2]; on = p2[4 * P2E + e2];
        }
        float yr[2];
#pragma unroll
        for (int c = 0; c < 2; c++) {
            float u1 = (float)u1c[c], u2 = (float)u2c[c];
            float f1 = (float)f1c[c], f2 = (float)f2c[c];
            float o  = (float)oc[c];
            float c1p = c1[c];
            c1[c] = fmaf(c1p, f1, u1);
            c2[c] = fmaf(c2[c], f2, (eps[c] + c1p) * u2);
            float cs = fmaf(c1[c], rho0[c], c2[c] * rho1[c]);
            float y = o * cs;
            y = fminf(9.0f, fmaxf(-9.0f, y));
            float ex = __expf(2.0f * y);
            yr[c] = (ex - 1.0f) / (ex + 1.0f);   // tanh(y)
        }
        *(float2*)(out + eo) = make_float2(yr[0], yr[1]);
        eo += CHAINS;
    }
}

extern "C" void kernel_launch(void* const* d_in, const int* in_sizes, int n_in,
                              void* d_out, int out_size, void* d_ws, size_t ws_size,
                              hipStream_t stream) {
    const float* x    = (const float*)d_in[0];
    const float* wgt  = (const float*)d_in[1];
    const float* bias = (const float*)d_in[2];
    const float* beps = (const float*)d_in[3];
    const float* bfin = (const float*)d_in[4];
    float* out = (float*)d_out;

    // Workspace layout (~124 MB)
    char* p = (char*)d_ws;
    _Float16* wT     = (_Float16*)p; p += (size_t)NCOL * NIN * 2;        // 5 MB
    _Float16* xb     = (_Float16*)p; p += (size_t)MTOT * NIN * 2;        // 32 MB
    _Float16* planes = (_Float16*)p; p += 5 * PLANE * 2;                 // 80 MB
    float* SM        = (float*)p;    p += 5 * SMP * 4;                   // 5 MB
    float* segc      = (float*)p;    p += 2 * SMP * 4;                   // 2 MB

    transpose_w_k<<<dim3(NCOL / 32, NIN / 32), 256, 0, stream>>>(wgt, wT);

    int n8 = MTOT * NIN / 8;
    convert_x_k<<<dim3((n8 + 255) / 256), 256, 0, stream>>>(x, xb, n8);

    gemm_gates_k<<<dim3(MTOT / BM, NCOL / BN), 256, 0, stream>>>(xb, wT, bias, planes);

    compose_k<<<dim3(SEG * CHAINS / 2 / 256), 256, 0, stream>>>(planes, beps, SM);
    segscan_k<<<dim3(CHAINS / 256), 256, 0, stream>>>(SM, segc, out);
    apply_k<<<dim3(SEG * CHAINS / 2 / 256), 256, 0, stream>>>(planes, segc, beps, bfin, out);
}

// Round 4
// 272.397 us; speedup vs baseline: 1.5219x; 1.5219x over previous
//
#include <hip/hip_runtime.h>
#include <cstdint>

// Problem constants
#define LSEQ 1024
#define BATCH 16
#define NIN 1024
#define NOUT 512
#define KGATE 5
#define NCOL (NOUT * KGATE)           // 2560
#define MTOT (LSEQ * BATCH)           // 16384
#define CHAINS (BATCH * NOUT)         // 8192
#define OUT_GCS (LSEQ * BATCH * NOUT) // 8388608
#define SEG 32                        // segments
#define SLEN 32                       // steps per segment
#define PLANE ((size_t)MTOT * NOUT)   // elements per gate plane (8M)
#define SMP ((size_t)SEG * CHAINS)    // elements per segmap plane (256K)

// GEMM geometry: m97-family TLP structure, 1-ahead staged dbuf
#define BM 256
#define BN 128
#define BK 32
#define NT (NIN / BK)                 // 32 K-tiles

typedef _Float16 f16x8 __attribute__((ext_vector_type(8)));
typedef _Float16 f16x4 __attribute__((ext_vector_type(4)));
typedef _Float16 f16x2 __attribute__((ext_vector_type(2)));
typedef float f32x4 __attribute__((ext_vector_type(4)));

__device__ __forceinline__ void async16(const void* g, void* l) {
    __builtin_amdgcn_global_load_lds(
        (const __attribute__((address_space(1))) void*)(uintptr_t)g,
        (__attribute__((address_space(3))) void*)(uintptr_t)l,
        16, 0, 0);
}

__device__ __forceinline__ float fsigmoid(float x) {
    return 1.0f / (1.0f + __expf(-x));
}

// ---------------- Kernel 1: convert x fp32 -> f16 (8 elems/thread) ----------------
__global__ void convert_x_k(const float* __restrict__ x, _Float16* __restrict__ xb, int n8) {
    int i = blockIdx.x * blockDim.x + threadIdx.x;
    if (i < n8) {
        float4 a = ((const float4*)x)[2 * i];
        float4 b = ((const float4*)x)[2 * i + 1];
        f16x8 h;
        h[0] = (_Float16)a.x; h[1] = (_Float16)a.y; h[2] = (_Float16)a.z; h[3] = (_Float16)a.w;
        h[4] = (_Float16)b.x; h[5] = (_Float16)b.y; h[6] = (_Float16)b.z; h[7] = (_Float16)b.w;
        ((f16x8*)xb)[i] = h;
    }
}

// ---------------- Kernel 2: transpose+convert+PERMUTE weight ----------------
// w [1024][2560] f32 -> wT [2560][1024] f16; orig col c=n*5+g -> row' = g*512+n
__global__ __launch_bounds__(256) void transpose_w_k(const float* __restrict__ w, _Float16* __restrict__ wT) {
    __shared__ float lds[32][33];
    int t = threadIdx.x;
    int col = t & 31;
    int rowg = t >> 5;
    int n0 = blockIdx.x * 32;
    int k0 = blockIdx.y * 32;
#pragma unroll
    for (int i = 0; i < 4; i++) {
        int r = rowg + i * 8;
        lds[r][col] = w[(size_t)(k0 + r) * NCOL + n0 + col];
    }
    __syncthreads();
#pragma unroll
    for (int i = 0; i < 4; i++) {
        int r = rowg + i * 8;
        int c = n0 + r;
        int row = (c % 5) * NOUT + (c / 5);
        wT[(size_t)row * NIN + k0 + col] = (_Float16)lds[col][r];
    }
}

// ---------------- Kernel 3: MFMA GEMM 256x128, BK=32, 1-ahead dbuf ----------------
// A: xb [16384][1024] f16; BT: wT [2560][1024] f16 (gate-plane-permuted cols)
// Per tile: stage(t+1 -> other slot) issued FIRST (max latency distance), then
// ds_read 12 b128 (XOR-swizzled) + 32 MFMA, then ONE __syncthreads
// (vmcnt+lgkm drain + barrier = slot handoff). Staging latency is covered by
// current tile's compute + 3-block/CU TLP (m114 overlap).
// __launch_bounds__(256, 2): round-3's (256,3) squeezed VGPRs to 84 -> K-loop
// scratch spills (~9 dwords/iter/thread -> +450 MB HBM traffic, 2x slowdown).
// (256,2) lets the allocator use its natural ~120 VGPRs (no spill); occupancy
// is still 3 blocks/CU via LDS (48 KiB) and VGPR<=168.
// LDS swizzle: 16B-chunk k' = k ^ ((row>>1)&3). Combined with the row-parity
// bank bit, 16 consecutive rows hit bank-quad 4*(row&1) + (k^((row>>1)&3)):
// all 8 quads, 2 lanes each -> conflict-free b128 (2-way is free, m136).
// MFMA operands SWAPPED (bf, af) -> acc holds C^T fragments: each lane owns 4
// consecutive n at fixed m -> f16x4 stores (4x fewer insts, 32B segments).
__global__ __launch_bounds__(256, 2) void gemm_gates_k(const _Float16* __restrict__ A,
                                                       const _Float16* __restrict__ BT,
                                                       const float* __restrict__ bias,
                                                       _Float16* __restrict__ planes) {
    // 48 KiB: A slots [2][8192] f16 at byte 0; B slots [2][4096] f16 at byte 32768
    __shared__ _Float16 lds[24576];
    const int t = threadIdx.x;
    const int w = t >> 6, lane = t & 63;
    const int q = lane >> 4, r16 = lane & 15;
    const int wm = (w >> 1) * 128, wn = (w & 1) * 64;
    const int m0 = blockIdx.x * BM, n0 = blockIdx.y * BN;

    // Loop-invariant per-lane LDS read byte bases (row*64B + swizzled 16B chunk).
    // Read rows differ from r16 by multiples of 16 -> (row>>1)&3 == (r16>>1)&3.
    const int swz = (q ^ ((r16 >> 1) & 3)) << 4;
    const int aBase = (wm + r16) * 64 + swz;            // + i*1024 + cur*16384
    const int bBase = 32768 + (wn + r16) * 64 + swz;    // + j*1024 + cur*8192

    // Staging: A 1024 chunks (4/thread), B 512 chunks (2/thread); chunk c = t + L*256,
    // r = c>>2 = rS + L*64, kc = c&3 = t&3; source chunk pre-swizzled kc^((r>>1)&3)
    // (lane-constant across L since L*64 is a multiple of 8 rows).
    const int rS = t >> 2;
    const int skS = (t & 3) ^ ((rS >> 1) & 3);
    const _Float16* aS = A + (size_t)(m0 + rS) * NIN + skS * 8;
    const _Float16* bS = BT + (size_t)(n0 + rS) * NIN + skS * 8;
    char* const ldsb = (char*)lds;
    const int aDst = t * 16;             // + L*4096 + nxt*16384
    const int bDst = 32768 + t * 16;     // + L*4096 + nxt*8192

    auto stage = [&](int tile, int nxt) {
        const _Float16* ap = aS + (size_t)tile * BK;
        const _Float16* bp = bS + (size_t)tile * BK;
#pragma unroll
        for (int L = 0; L < 4; L++)
            async16(ap + (size_t)L * 64 * NIN, ldsb + nxt * 16384 + aDst + L * 4096);
#pragma unroll
        for (int L = 0; L < 2; L++)
            async16(bp + (size_t)L * 64 * NIN, ldsb + nxt * 8192 + bDst + L * 4096);
    };

    f32x4 acc[8][4] = {};

    // Prologue: stage tile 0 -> slot 0
    stage(0, 0);
    __syncthreads();

#pragma unroll 2
    for (int tt = 0; tt < NT; tt++) {
        const int cur = tt & 1;
        // stage next tile into the other slot FIRST (max issue->wait distance)
        if (tt + 1 < NT) stage(tt + 1, cur ^ 1);

        f16x8 af[8], bf[4];
        const char* ab = ldsb + cur * 16384 + aBase;
        const char* bb = ldsb + cur * 8192 + bBase;
#pragma unroll
        for (int i = 0; i < 8; i++) af[i] = *(const f16x8*)(ab + i * 1024);
#pragma unroll
        for (int j = 0; j < 4; j++) bf[j] = *(const f16x8*)(bb + j * 1024);

        __builtin_amdgcn_s_setprio(1);
#pragma unroll
        for (int i = 0; i < 8; i++)
#pragma unroll
            for (int j = 0; j < 4; j++)
                acc[i][j] = __builtin_amdgcn_mfma_f32_16x16x32_f16(bf[j], af[i], acc[i][j], 0, 0, 0);
        __builtin_amdgcn_s_setprio(0);

        // one barrier per tile: drains vmcnt (next tile staged) + slot handoff
        __syncthreads();
    }

    // Epilogue: acc[i][j] = C^T frag: m = wm + i*16 + r16, n = wn + j*16 + q*4 + reg
    const int g = n0 >> 9;            // block spans 128 cols within one 512-gate
    const int nb = n0 & (NOUT - 1);
    _Float16* plane = planes + (size_t)g * PLANE;
#pragma unroll
    for (int i = 0; i < 8; i++) {
        int m = m0 + wm + i * 16 + r16;
        _Float16* prow = plane + (size_t)m * NOUT + nb;
#pragma unroll
        for (int j = 0; j < 4; j++) {
            int nn = wn + j * 16 + q * 4;
            float4 bv = *(const float4*)(bias + n0 + nn);
            f16x4 hv;
#pragma unroll
            for (int reg = 0; reg < 4; reg++) {
                float v = acc[i][j][reg];
                float b = (reg == 0) ? bv.x : (reg == 1) ? bv.y : (reg == 2) ? bv.z : bv.w;
                if (g >= 2) v = fsigmoid(v + b);
                hv[reg] = (_Float16)v;
            }
            *(f16x4*)(prow + nn) = hv;
        }
    }
}

// ---------------- Kernel 4a: compose per-segment affine maps ----------------
// 2 chains/thread (8 waves/CU) + 1-deep register prefetch of next step's vectors.
// map: c' = A c + b, A=[[f1,0],[u2,f2]], b=[u1, eps*u2]
// SM planes: 0:a11 1:a21 2:a22 3:b1 4:b2, each [SEG][CHAINS] f32
__global__ __launch_bounds__(256) void compose_k(const _Float16* __restrict__ planes,
                                                 const float* __restrict__ beps,
                                                 float* __restrict__ SM) {
    int u = blockIdx.x * 256 + threadIdx.x;       // 0 .. SEG*CHAINS/2 - 1
    int t2 = u & (CHAINS / 2 - 1);
    int s = u >> 12;
    int tch = t2 << 1;
    int n = tch & (NOUT - 1);
    float eps[2] = { fsigmoid(beps[n]), fsigmoid(beps[n + 1]) };
    float a11[2] = {1.0f, 1.0f}, a21[2] = {}, a22[2] = {1.0f, 1.0f}, b1[2] = {}, b2[2] = {};
    const f16x2* p2 = (const f16x2*)planes;
    const size_t P2E = PLANE >> 1;
    const size_t estep = CHAINS >> 1;
    size_t e = ((size_t)(s * SLEN) * CHAINS + tch) >> 1;
    f16x2 u1n = p2[e], u2n = p2[P2E + e], f1n = p2[2 * P2E + e], f2n = p2[3 * P2E + e];
#pragma unroll 4
    for (int j = 0; j < SLEN; j++) {
        f16x2 u1c = u1n, u2c = u2n, f1c = f1n, f2c = f2n;
        if (j + 1 < SLEN) {
            e += estep;
            u1n = p2[e]; u2n = p2[P2E + e]; f1n = p2[2 * P2E + e]; f2n = p2[3 * P2E + e];
        }
#pragma unroll
        for (int c = 0; c < 2; c++) {
            float u1 = (float)u1c[c], u2 = (float)u2c[c];
            float f1 = (float)f1c[c], f2 = (float)f2c[c];
            float na11 = f1 * a11[c];
            float na21 = fmaf(u2, a11[c], f2 * a21[c]);
            float na22 = f2 * a22[c];
            float nb1  = fmaf(f1, b1[c], u1);
            float nb2  = fmaf(u2, b1[c], fmaf(f2, b2[c], eps[c] * u2));
            a11[c] = na11; a21[c] = na21; a22[c] = na22; b1[c] = nb1; b2[c] = nb2;
        }
    }
    size_t idx = (size_t)s * CHAINS + tch;
    *(float2*)(SM + idx)           = make_float2(a11[0], a11[1]);
    *(float2*)(SM + SMP + idx)     = make_float2(a21[0], a21[1]);
    *(float2*)(SM + 2 * SMP + idx) = make_float2(a22[0], a22[1]);
    *(float2*)(SM + 3 * SMP + idx) = make_float2(b1[0], b1[1]);
    *(float2*)(SM + 4 * SMP + idx) = make_float2(b2[0], b2[1]);
}

// ---------------- Kernel 4b: sequential scan over segment maps (prefetched) ----------------
__global__ __launch_bounds__(256) void segscan_k(const float* __restrict__ SM,
                                                 float* __restrict__ segc,
                                                 float* __restrict__ out) {
    int t = blockIdx.x * 256 + threadIdx.x;  // 0..8191
    float c1 = 0.0f, c2 = 0.0f;
    float a11n = SM[t], a21n = SM[SMP + t], a22n = SM[2 * SMP + t];
    float b1n = SM[3 * SMP + t], b2n = SM[4 * SMP + t];
#pragma unroll
    for (int s = 0; s < SEG; s++) {
        float a11 = a11n, a21 = a21n, a22 = a22n, b1 = b1n, b2 = b2n;
        if (s + 1 < SEG) {
            size_t nx = (size_t)(s + 1) * CHAINS + t;
            a11n = SM[nx]; a21n = SM[SMP + nx]; a22n = SM[2 * SMP + nx];
            b1n = SM[3 * SMP + nx]; b2n = SM[4 * SMP + nx];
        }
        size_t idx = (size_t)s * CHAINS + t;
        segc[idx] = c1;
        segc[SMP + idx] = c2;
        float c1n = fmaf(a11, c1, b1);
        float c2n = fmaf(a21, c1, fmaf(a22, c2, b2));
        c1 = c1n; c2 = c2n;
    }
    out[OUT_GCS + t] = c1;
    out[OUT_GCS + CHAINS + t] = c2;
}

// ---------------- Kernel 4c: apply within segments + fused output ----------------
// 2 chains/thread + 1-deep register prefetch.
__global__ __launch_bounds__(256) void apply_k(const _Float16* __restrict__ planes,
                                               const float* __restrict__ segc,
                                               const float* __restrict__ beps,
                                               const float* __restrict__ bfin,
                                               float* __restrict__ out) {
    int u = blockIdx.x * 256 + threadIdx.x;
    int t2 = u & (CHAINS / 2 - 1);
    int s = u >> 12;
    int tch = t2 << 1;
    int n = tch & (NOUT - 1);
    float eps[2], rho0[2], rho1[2], c1[2], c2[2];
#pragma unroll
    for (int c = 0; c < 2; c++) {
        eps[c]  = fsigmoid(beps[n + c]);
        rho0[c] = 2.0f * fsigmoid(bfin[2 * (n + c)]);
        rho1[c] = 2.0f * fsigmoid(bfin[2 * (n + c) + 1]);
    }
    size_t idx = (size_t)s * CHAINS + tch;
    float2 c1v = *(const float2*)(segc + idx);
    float2 c2v = *(const float2*)(segc + SMP + idx);
    c1[0] = c1v.x; c1[1] = c1v.y; c2[0] = c2v.x; c2[1] = c2v.y;
    const f16x2* p2 = (const f16x2*)planes;
    const size_t P2E = PLANE >> 1;
    const size_t estep = CHAINS >> 1;
    size_t e2 = ((size_t)(s * SLEN) * CHAINS + tch) >> 1;
    size_t eo = (size_t)(s * SLEN) * CHAINS + tch;
    f16x2 u1n = p2[e2], u2n = p2[P2E + e2], f1n = p2[2 * P2E + e2],
          f2n = p2[3 * P2E + e2], on = p2[4 * P2E + e2];
#pragma unroll 4
    for (int j = 0; j < SLEN; j++) {
        f16x2 u1c = u1n, u2c = u2n, f1c = f1n, f2c = f2n, oc = on;
        if (j + 1 < SLEN) {
            e2 += estep;
            u1n = p2[e2]; u2n = p2[P2E + e2]; f1n = p2[2 * P2E + e2];
            f2n = p2[3 * P2E + e2]; on = p2[4 * P2E + e2];
        }
        float yr[2];
#pragma unroll
        for (int c = 0; c < 2; c++) {
            float u1 = (float)u1c[c], u2 = (float)u2c[c];
            float f1 = (float)f1c[c], f2 = (float)f2c[c];
            float o  = (float)oc[c];
            float c1p = c1[c];
            c1[c] = fmaf(c1p, f1, u1);
            c2[c] = fmaf(c2[c], f2, (eps[c] + c1p) * u2);
            float cs = fmaf(c1[c], rho0[c], c2[c] * rho1[c]);
            float y = o * cs;
            y = fminf(9.0f, fmaxf(-9.0f, y));
            float ex = __expf(2.0f * y);
            yr[c] = (ex - 1.0f) / (ex + 1.0f);   // tanh(y)
        }
        *(float2*)(out + eo) = make_float2(yr[0], yr[1]);
        eo += CHAINS;
    }
}

extern "C" void kernel_launch(void* const* d_in, const int* in_sizes, int n_in,
                              void* d_out, int out_size, void* d_ws, size_t ws_size,
                              hipStream_t stream) {
    const float* x    = (const float*)d_in[0];
    const float* wgt  = (const float*)d_in[1];
    const float* bias = (const float*)d_in[2];
    const float* beps = (const float*)d_in[3];
    const float* bfin = (const float*)d_in[4];
    float* out = (float*)d_out;

    // Workspace layout (~124 MB)
    char* p = (char*)d_ws;
    _Float16* wT     = (_Float16*)p; p += (size_t)NCOL * NIN * 2;        // 5 MB
    _Float16* xb     = (_Float16*)p; p += (size_t)MTOT * NIN * 2;        // 32 MB
    _Float16* planes = (_Float16*)p; p += 5 * PLANE * 2;                 // 80 MB
    float* SM        = (float*)p;    p += 5 * SMP * 4;                   // 5 MB
    float* segc      = (float*)p;    p += 2 * SMP * 4;                   // 2 MB

    transpose_w_k<<<dim3(NCOL / 32, NIN / 32), 256, 0, stream>>>(wgt, wT);

    int n8 = MTOT * NIN / 8;
    convert_x_k<<<dim3((n8 + 255) / 256), 256, 0, stream>>>(x, xb, n8);

    gemm_gates_k<<<dim3(MTOT / BM, NCOL / BN), 256, 0, stream>>>(xb, wT, bias, planes);

    compose_k<<<dim3(SEG * CHAINS / 2 / 256), 256, 0, stream>>>(planes, beps, SM);
    segscan_k<<<dim3(CHAINS / 256), 256, 0, stream>>>(SM, segc, out);
    apply_k<<<dim3(SEG * CHAINS / 2 / 256), 256, 0, stream>>>(planes, segc, beps, bfin, out);
}

// Round 8
// 269.473 us; speedup vs baseline: 1.5384x; 1.0108x over previous
//
#include <hip/hip_runtime.h>
#include <cstdint>

// Problem constants
#define LSEQ 1024
#define BATCH 16
#define NIN 1024
#define NOUT 512
#define KGATE 5
#define NCOL (NOUT * KGATE)           // 2560
#define MTOT (LSEQ * BATCH)           // 16384
#define CHAINS (BATCH * NOUT)         // 8192
#define OUT_GCS (LSEQ * BATCH * NOUT) // 8388608
#define SEG 32                        // segments
#define SLEN 32                       // steps per segment
#define PLANE ((size_t)MTOT * NOUT)   // elements per gate plane (8M)
#define SMP ((size_t)SEG * CHAINS)    // elements per segmap plane (256K)

// GEMM geometry: m97-family TLP structure, 1-ahead staged dbuf
#define BM 256
#define BN 128
#define BK 32
#define NT (NIN / BK)                 // 32 K-tiles

// Scan-kernel tiling: per block = 1 segment x 256 chains, staged in LDS
#define CGRP 256                      // chains per block
#define JPH 8                         // steps per staged phase (4 phases = SLEN)

typedef _Float16 f16x8 __attribute__((ext_vector_type(8)));
typedef _Float16 f16x4 __attribute__((ext_vector_type(4)));
typedef float f32x4 __attribute__((ext_vector_type(4)));

__device__ __forceinline__ void async16(const void* g, void* l) {
    __builtin_amdgcn_global_load_lds(
        (const __attribute__((address_space(1))) void*)(uintptr_t)g,
        (__attribute__((address_space(3))) void*)(uintptr_t)l,
        16, 0, 0);
}

__device__ __forceinline__ float fsigmoid(float x) {
    return 1.0f / (1.0f + __expf(-x));
}

// ---------------- Kernel 1: convert x fp32 -> f16 (8 elems/thread) ----------------
__global__ void convert_x_k(const float* __restrict__ x, _Float16* __restrict__ xb, int n8) {
    int i = blockIdx.x * blockDim.x + threadIdx.x;
    if (i < n8) {
        float4 a = ((const float4*)x)[2 * i];
        float4 b = ((const float4*)x)[2 * i + 1];
        f16x8 h;
        h[0] = (_Float16)a.x; h[1] = (_Float16)a.y; h[2] = (_Float16)a.z; h[3] = (_Float16)a.w;
        h[4] = (_Float16)b.x; h[5] = (_Float16)b.y; h[6] = (_Float16)b.z; h[7] = (_Float16)b.w;
        ((f16x8*)xb)[i] = h;
    }
}

// ---------------- Kernel 2: transpose+convert+PERMUTE weight ----------------
// w [1024][2560] f32 -> wT [2560][1024] f16; orig col c=n*5+g -> row' = g*512+n
__global__ __launch_bounds__(256) void transpose_w_k(const float* __restrict__ w, _Float16* __restrict__ wT) {
    __shared__ float lds[32][33];
    int t = threadIdx.x;
    int col = t & 31;
    int rowg = t >> 5;
    int n0 = blockIdx.x * 32;
    int k0 = blockIdx.y * 32;
#pragma unroll
    for (int i = 0; i < 4; i++) {
        int r = rowg + i * 8;
        lds[r][col] = w[(size_t)(k0 + r) * NCOL + n0 + col];
    }
    __syncthreads();
#pragma unroll
    for (int i = 0; i < 4; i++) {
        int r = rowg + i * 8;
        int c = n0 + r;
        int row = (c % 5) * NOUT + (c / 5);
        wT[(size_t)row * NIN + k0 + col] = (_Float16)lds[col][r];
    }
}

// ---------------- Kernel 3: MFMA GEMM 256x128, BK=32, 1-ahead dbuf ----------------
// (byte-identical to round 4: 113 us, MfmaUtil 33%, 0 bank conflicts, no spills)
__global__ __launch_bounds__(256, 2) void gemm_gates_k(const _Float16* __restrict__ A,
                                                       const _Float16* __restrict__ BT,
                                                       const float* __restrict__ bias,
                                                       _Float16* __restrict__ planes) {
    // 48 KiB: A slots [2][8192] f16 at byte 0; B slots [2][4096] f16 at byte 32768
    __shared__ _Float16 lds[24576];
    const int t = threadIdx.x;
    const int w = t >> 6, lane = t & 63;
    const int q = lane >> 4, r16 = lane & 15;
    const int wm = (w >> 1) * 128, wn = (w & 1) * 64;
    const int m0 = blockIdx.x * BM, n0 = blockIdx.y * BN;

    const int swz = (q ^ ((r16 >> 1) & 3)) << 4;
    const int aBase = (wm + r16) * 64 + swz;            // + i*1024 + cur*16384
    const int bBase = 32768 + (wn + r16) * 64 + swz;    // + j*1024 + cur*8192

    const int rS = t >> 2;
    const int skS = (t & 3) ^ ((rS >> 1) & 3);
    const _Float16* aS = A + (size_t)(m0 + rS) * NIN + skS * 8;
    const _Float16* bS = BT + (size_t)(n0 + rS) * NIN + skS * 8;
    char* const ldsb = (char*)lds;
    const int aDst = t * 16;             // + L*4096 + nxt*16384
    const int bDst = 32768 + t * 16;     // + L*4096 + nxt*8192

    auto stage = [&](int tile, int nxt) {
        const _Float16* ap = aS + (size_t)tile * BK;
        const _Float16* bp = bS + (size_t)tile * BK;
#pragma unroll
        for (int L = 0; L < 4; L++)
            async16(ap + (size_t)L * 64 * NIN, ldsb + nxt * 16384 + aDst + L * 4096);
#pragma unroll
        for (int L = 0; L < 2; L++)
            async16(bp + (size_t)L * 64 * NIN, ldsb + nxt * 8192 + bDst + L * 4096);
    };

    f32x4 acc[8][4] = {};

    stage(0, 0);
    __syncthreads();

#pragma unroll 2
    for (int tt = 0; tt < NT; tt++) {
        const int cur = tt & 1;
        if (tt + 1 < NT) stage(tt + 1, cur ^ 1);

        f16x8 af[8], bf[4];
        const char* ab = ldsb + cur * 16384 + aBase;
        const char* bb = ldsb + cur * 8192 + bBase;
#pragma unroll
        for (int i = 0; i < 8; i++) af[i] = *(const f16x8*)(ab + i * 1024);
#pragma unroll
        for (int j = 0; j < 4; j++) bf[j] = *(const f16x8*)(bb + j * 1024);

        __builtin_amdgcn_s_setprio(1);
#pragma unroll
        for (int i = 0; i < 8; i++)
#pragma unroll
            for (int j = 0; j < 4; j++)
                acc[i][j] = __builtin_amdgcn_mfma_f32_16x16x32_f16(bf[j], af[i], acc[i][j], 0, 0, 0);
        __builtin_amdgcn_s_setprio(0);

        __syncthreads();
    }

    // Epilogue: acc[i][j] = C^T frag: m = wm + i*16 + r16, n = wn + j*16 + q*4 + reg
    const int g = n0 >> 9;
    const int nb = n0 & (NOUT - 1);
    _Float16* plane = planes + (size_t)g * PLANE;
#pragma unroll
    for (int i = 0; i < 8; i++) {
        int m = m0 + wm + i * 16 + r16;
        _Float16* prow = plane + (size_t)m * NOUT + nb;
#pragma unroll
        for (int j = 0; j < 4; j++) {
            int nn = wn + j * 16 + q * 4;
            float4 bv = *(const float4*)(bias + n0 + nn);
            f16x4 hv;
#pragma unroll
            for (int reg = 0; reg < 4; reg++) {
                float v = acc[i][j][reg];
                float b = (reg == 0) ? bv.x : (reg == 1) ? bv.y : (reg == 2) ? bv.z : bv.w;
                if (g >= 2) v = fsigmoid(v + b);
                hv[reg] = (_Float16)v;
            }
            *(f16x4*)(prow + nn) = hv;
        }
    }
}

// ---------------- Kernel 4a: compose per-segment affine maps (reg-staged LDS) ----------------
// Block = 1 segment x 256 chains; double-buffered 32 KB LDS tile, reg-staged.
// ROOT CAUSE of rounds 5-7's deterministic failure (fixed here): the last two
// compute calls passed the PHASE number (2,3) as the BUFFER index -> tile[2]/
// tile[3] out-of-bounds LDS reads (zeros) -> SM collapsed to 0 -> outputs 1/2
// zero (absmax 468) and output 0 carried wrong (2.0). Buffer schedule is
// buf0:{ph0,ph2}, buf1:{ph1,ph3} -> calls must be (0),(1),(0),(1).
// Thread t stages plane r, step j=t>>5, chains (t&31)*8..+7:
// LDS byte (t + r*256)*16 == &tile[b][r][j][(t&31)*8]  (verified identity).
// map: c' = A c + b, A=[[f1,0],[u2,f2]], b=[u1, eps*u2]
// SM planes: 0:a11 1:a21 2:a22 3:b1 4:b2, each [SEG][CHAINS] f32
__global__ __launch_bounds__(256) void compose_k(const _Float16* __restrict__ planes,
                                                 const float* __restrict__ beps,
                                                 float* __restrict__ SM) {
    __shared__ _Float16 tile[2][4][JPH][CGRP];   // 32 KB
    const int t = threadIdx.x;
    const int s = blockIdx.x >> 5;               // segment
    const int grp = blockIdx.x & 31;             // chain group
    const int tch = grp * CGRP + t;
    const int n = tch & (NOUT - 1);
    const int jl = t >> 5, ci = t & 31;

    auto stage = [&](int ph, int b) {
        const int j0 = s * SLEN + ph * JPH;
        f16x8 v[4];
#pragma unroll
        for (int r = 0; r < 4; r++)
            v[r] = *(const f16x8*)(planes + (size_t)r * PLANE + (size_t)(j0 + jl) * CHAINS + grp * CGRP + ci * 8);
#pragma unroll
        for (int r = 0; r < 4; r++)
            *(f16x8*)((char*)tile + b * 16384 + (t + r * 256) * 16) = v[r];
    };

    float eps = fsigmoid(beps[n]);
    float a11 = 1.0f, a21 = 0.0f, a22 = 1.0f, b1 = 0.0f, b2 = 0.0f;

    auto computeph = [&](int b) {
#pragma unroll
        for (int j = 0; j < JPH; j++) {
            float u1 = (float)tile[b][0][j][t];
            float u2 = (float)tile[b][1][j][t];
            float f1 = (float)tile[b][2][j][t];
            float f2 = (float)tile[b][3][j][t];
            float na11 = f1 * a11;
            float na21 = fmaf(u2, a11, f2 * a21);
            float na22 = f2 * a22;
            float nb1  = fmaf(f1, b1, u1);
            float nb2  = fmaf(u2, b1, fmaf(f2, b2, eps * u2));
            a11 = na11; a21 = na21; a22 = na22; b1 = nb1; b2 = nb2;
        }
    };

    stage(0, 0);
    stage(1, 1);
    __syncthreads();       // buf0+buf1 visible to every wave
    computeph(0);          // phase 0 from buf 0
    __syncthreads();       // all waves done reading buf 0
    stage(2, 0);
    __syncthreads();       // buf 0 = phase 2
    computeph(1);          // phase 1 from buf 1
    __syncthreads();       // all waves done reading buf 1
    stage(3, 1);
    __syncthreads();       // buf 1 = phase 3
    computeph(0);          // phase 2 from buf 0  (was OOB computeph(2))
    computeph(1);          // phase 3 from buf 1  (was OOB computeph(3))

    size_t idx = (size_t)s * CHAINS + tch;
    SM[idx]           = a11;
    SM[SMP + idx]     = a21;
    SM[2 * SMP + idx] = a22;
    SM[3 * SMP + idx] = b1;
    SM[4 * SMP + idx] = b2;
}

// ---------------- Kernel 4b: sequential scan over segment maps (prefetched) ----------------
__global__ __launch_bounds__(256) void segscan_k(const float* __restrict__ SM,
                                                 float* __restrict__ segc,
                                                 float* __restrict__ out) {
    int t = blockIdx.x * 256 + threadIdx.x;  // 0..8191
    float c1 = 0.0f, c2 = 0.0f;
    float a11n = SM[t], a21n = SM[SMP + t], a22n = SM[2 * SMP + t];
    float b1n = SM[3 * SMP + t], b2n = SM[4 * SMP + t];
#pragma unroll
    for (int s = 0; s < SEG; s++) {
        float a11 = a11n, a21 = a21n, a22 = a22n, b1 = b1n, b2 = b2n;
        if (s + 1 < SEG) {
            size_t nx = (size_t)(s + 1) * CHAINS + t;
            a11n = SM[nx]; a21n = SM[SMP + nx]; a22n = SM[2 * SMP + nx];
            b1n = SM[3 * SMP + nx]; b2n = SM[4 * SMP + nx];
        }
        size_t idx = (size_t)s * CHAINS + t;
        segc[idx] = c1;
        segc[SMP + idx] = c2;
        float c1n = fmaf(a11, c1, b1);
        float c2n = fmaf(a21, c1, fmaf(a22, c2, b2));
        c1 = c1n; c2 = c2n;
    }
    out[OUT_GCS + t] = c1;
    out[OUT_GCS + CHAINS + t] = c2;
}

// ---------------- Kernel 4c: apply within segments + fused output (reg-staged LDS) ----------
// Same structure as compose, 5 planes: 40 KB LDS. (ph,b) calls were always correct here.
__global__ __launch_bounds__(256) void apply_k(const _Float16* __restrict__ planes,
                                               const float* __restrict__ segc,
                                               const float* __restrict__ beps,
                                               const float* __restrict__ bfin,
                                               float* __restrict__ out) {
    __shared__ _Float16 tile[2][5][JPH][CGRP];   // 40 KB
    const int t = threadIdx.x;
    const int s = blockIdx.x >> 5;
    const int grp = blockIdx.x & 31;
    const int tch = grp * CGRP + t;
    const int n = tch & (NOUT - 1);
    const int jl = t >> 5, ci = t & 31;

    auto stage = [&](int ph, int b) {
        const int j0 = s * SLEN + ph * JPH;
        f16x8 v[5];
#pragma unroll
        for (int r = 0; r < 5; r++)
            v[r] = *(const f16x8*)(planes + (size_t)r * PLANE + (size_t)(j0 + jl) * CHAINS + grp * CGRP + ci * 8);
#pragma unroll
        for (int r = 0; r < 5; r++)
            *(f16x8*)((char*)tile + b * 20480 + (t + r * 256) * 16) = v[r];
    };

    size_t idx = (size_t)s * CHAINS + tch;
    float c1 = segc[idx];
    float c2 = segc[SMP + idx];
    float eps  = fsigmoid(beps[n]);
    float rho0 = 2.0f * fsigmoid(bfin[2 * n]);
    float rho1 = 2.0f * fsigmoid(bfin[2 * n + 1]);

    auto computeph = [&](int ph, int b) {
        size_t eo = (size_t)(s * SLEN + ph * JPH) * CHAINS + tch;
#pragma unroll
        for (int j = 0; j < JPH; j++) {
            float u1 = (float)tile[b][0][j][t];
            float u2 = (float)tile[b][1][j][t];
            float f1 = (float)tile[b][2][j][t];
            float f2 = (float)tile[b][3][j][t];
            float o  = (float)tile[b][4][j][t];
            float c1p = c1;
            c1 = fmaf(c1p, f1, u1);
            c2 = fmaf(c2, f2, (eps + c1p) * u2);
            float cs = fmaf(c1, rho0, c2 * rho1);
            float y = o * cs;
            y = fminf(9.0f, fmaxf(-9.0f, y));
            float ex = __expf(2.0f * y);
            out[eo] = (ex - 1.0f) / (ex + 1.0f);   // tanh(y)
            eo += CHAINS;
        }
    };

    stage(0, 0);
    stage(1, 1);
    __syncthreads();       // buf0+buf1 visible
    computeph(0, 0);
    __syncthreads();       // all waves done reading buf 0
    stage(2, 0);
    __syncthreads();       // buf 0 = phase 2
    computeph(1, 1);
    __syncthreads();       // all waves done reading buf 1
    stage(3, 1);
    __syncthreads();       // buf 1 = phase 3
    computeph(2, 0);
    computeph(3, 1);
}

extern "C" void kernel_launch(void* const* d_in, const int* in_sizes, int n_in,
                              void* d_out, int out_size, void* d_ws, size_t ws_size,
                              hipStream_t stream) {
    const float* x    = (const float*)d_in[0];
    const float* wgt  = (const float*)d_in[1];
    const float* bias = (const float*)d_in[2];
    const float* beps = (const float*)d_in[3];
    const float* bfin = (const float*)d_in[4];
    float* out = (float*)d_out;

    // Workspace layout (~124 MB)
    char* p = (char*)d_ws;
    _Float16* wT     = (_Float16*)p; p += (size_t)NCOL * NIN * 2;        // 5 MB
    _Float16* xb     = (_Float16*)p; p += (size_t)MTOT * NIN * 2;        // 32 MB
    _Float16* planes = (_Float16*)p; p += 5 * PLANE * 2;                 // 80 MB
    float* SM        = (float*)p;    p += 5 * SMP * 4;                   // 5 MB
    float* segc      = (float*)p;    p += 2 * SMP * 4;                   // 2 MB

    transpose_w_k<<<dim3(NCOL / 32, NIN / 32), 256, 0, stream>>>(wgt, wT);

    int n8 = MTOT * NIN / 8;
    convert_x_k<<<dim3((n8 + 255) / 256), 256, 0, stream>>>(x, xb, n8);

    gemm_gates_k<<<dim3(MTOT / BM, NCOL / BN), 256, 0, stream>>>(xb, wT, bias, planes);

    compose_k<<<dim3(SEG * (CHAINS / CGRP)), 256, 0, stream>>>(planes, beps, SM);
    segscan_k<<<dim3(CHAINS / 256), 256, 0, stream>>>(SM, segc, out);
    apply_k<<<dim3(SEG * (CHAINS / CGRP)), 256, 0, stream>>>(planes, segc, beps, bfin, out);
}